// Round 18
// baseline (112.805 us; speedup 1.0000x reference)
//
#include <hip/hip_runtime.h>

typedef __attribute__((ext_vector_type(8))) short bf16x8;
typedef __attribute__((ext_vector_type(4))) float f32x4;
typedef __attribute__((ext_vector_type(4))) unsigned short u16x4;
typedef unsigned short u16;
typedef unsigned int u32;

static __device__ __forceinline__ u16 f2bf(float f) {
  u32 u = __float_as_uint(f);
  u32 r = (u + 0x7fffu + ((u >> 16) & 1u)) >> 16;  // RNE
  return (u16)r;
}

static __device__ __forceinline__ u32 cvt_pk(float lo, float hi) {
  u32 r;
  asm("v_cvt_pk_bf16_f32 %0, %1, %2" : "=v"(r) : "v"(lo), "v"(hi));
  return r;
}

#define GLDS16(g, l)                                                        \
  __builtin_amdgcn_global_load_lds(                                         \
      (const __attribute__((address_space(1))) u32*)(g),                    \
      (__attribute__((address_space(3))) u32*)(l), 16, 0, 0)

#define WAIT_VM5() asm volatile("s_waitcnt vmcnt(5)" ::: "memory")
#define WAIT_VM0() asm volatile("s_waitcnt vmcnt(0)" ::: "memory")
#define RAWBAR() __builtin_amdgcn_s_barrier()

#define SC2F 0.18033688011112042f  // 0.125 * log2(e)

// ---------------- fused cast kernel ----------------
__global__ __launch_bounds__(256) void cast_all(const float* __restrict__ x,
                                                const float* __restrict__ wq,
                                                const float* __restrict__ wk,
                                                const float* __restrict__ wv,
                                                const float* __restrict__ wo,
                                                u16* __restrict__ xb,
                                                u16* __restrict__ wqkv,
                                                u16* __restrict__ wot) {
  __shared__ u16 tile[64][66];
  int bid = blockIdx.x, t = threadIdx.x;
  if (bid < 2048) {
    int i = bid * 256 + t;
    const float4* xv = (const float4*)x;
    float4 a = xv[i * 2], b = xv[i * 2 + 1];
    bf16x8 o;
    o[0] = f2bf(a.x); o[1] = f2bf(a.y); o[2] = f2bf(a.z); o[3] = f2bf(a.w);
    o[4] = f2bf(b.x); o[5] = f2bf(b.y); o[6] = f2bf(b.z); o[7] = f2bf(b.w);
    *(bf16x8*)(xb + i * 8) = o;
    return;
  }
  const float* src;
  u16* dstb;
  if (bid < 2816) {
    int id = bid - 2048;  // 768 = sel(3) * h(16) * dt(16)
    int dt = id & 15, h = (id >> 4) & 15, sel = id >> 8;
    src = (sel == 0 ? wq : (sel == 1 ? wk : wv)) + h * 65536 + dt * 4096;
    dstb = wqkv + ((size_t)(h * 192 + sel * 64)) * 1024 + dt * 64;
    int r = t >> 4, c4 = (t & 15) * 4;
#pragma unroll
    for (int p = 0; p < 4; ++p) {
      int rr = r + p * 16;
      float4 v = *(const float4*)(src + rr * 64 + c4);
      u16x4 o;
      o[0] = f2bf(v.x); o[1] = f2bf(v.y); o[2] = f2bf(v.z); o[3] = f2bf(v.w);
      *(u16x4*)&tile[rr][c4] = o;  // tile[d][kk]
    }
  } else {
    int id = bid - 2816;  // 256 = kt(16) * nt(16)
    int nt = id & 15, kt = id >> 4;
    src = wo + (size_t)(kt * 64) * 1024 + nt * 64;
    dstb = wot + (size_t)(nt * 64) * 1024 + kt * 64;
    int r = t >> 4, c4 = (t & 15) * 4;
#pragma unroll
    for (int p = 0; p < 4; ++p) {
      int rr = r + p * 16;
      float4 v = *(const float4*)(src + (size_t)rr * 1024 + c4);
      u16x4 o;
      o[0] = f2bf(v.x); o[1] = f2bf(v.y); o[2] = f2bf(v.z); o[3] = f2bf(v.w);
      *(u16x4*)&tile[rr][c4] = o;
    }
  }
  __syncthreads();
  int nn = t >> 3, dc = (t & 7) * 8;
#pragma unroll
  for (int p = 0; p < 2; ++p) {
    int np = nn + p * 32;
    u16x4 a, b2;
#pragma unroll
    for (int i = 0; i < 4; ++i) {
      a[i] = tile[dc + i][np];
      b2[i] = tile[dc + 4 + i][np];
    }
    *(u16x4*)(dstb + (size_t)np * 1024 + dc) = a;
    *(u16x4*)(dstb + (size_t)np * 1024 + dc + 4) = b2;
  }
}

// ---------------- QKV GEMM: 128x192 tile, BK=32, 3-stage pipeline --------
// Proven BK=32 body (R10/R13/R14 addressing) + depth-2 prefetch: loop does
// {vmcnt(5) [tile-t landed, t+1 flying] -> barrier -> stage t+2 -> compute}.
// DMA gets 2 full compute-steps of latency cover. 3 x 20KB stages = 61KB
// LDS -> still 2 blocks/CU. bx-major XCD grouping (B-panel L2-resident).
__global__ __launch_bounds__(256) void gemm_qkv(const u16* __restrict__ A,
                                                const u16* __restrict__ Bt,
                                                u16* __restrict__ qkb,
                                                u16* __restrict__ Vt, int M,
                                                int N, int K) {
  const int t = threadIdx.x;
  const int lane = t & 63, w = t >> 6;
  const int lr = lane & 15, lg = lane >> 4;
  const int wr = w >> 1, wc = w & 1;
  int lin = blockIdx.y * gridDim.x + blockIdx.x;
  // bx-major XCD grouping (bijective for 512 = 8 * 2 * 32)
  int bx = 2 * (lin & 7) + ((lin >> 3) & 1);
  int by = lin >> 4;
  const int m0 = by * 128, n0 = bx * 192, head = bx;
  __shared__ __align__(16) u16 SM[30720];  // 3 stages x (A 4096 | B 6144) u16
  const int ra = t >> 2, ca = (t & 3) * 8;
  const u16* a0 = A + (size_t)(m0 + ra) * K + ca;
  const u16* b0 = Bt + (size_t)(n0 + ra) * K + ca;
  f32x4 acc[4][6] = {};

#define QSTAGE(sb, k0)                                                      \
  {                                                                         \
    GLDS16(a0 + (k0), &SM[(sb)*10240 + t * 8]);                             \
    GLDS16(a0 + (size_t)64 * K + (k0), &SM[(sb)*10240 + 2048 + t * 8]);     \
    GLDS16(b0 + (k0), &SM[(sb)*10240 + 4096 + t * 8]);                      \
    GLDS16(b0 + (size_t)64 * K + (k0), &SM[(sb)*10240 + 6144 + t * 8]);     \
    GLDS16(b0 + (size_t)128 * K + (k0), &SM[(sb)*10240 + 8192 + t * 8]);    \
  }

  QSTAGE(0, 0);
  QSTAGE(1, 32);
  for (int k0 = 0; k0 < K; k0 += 32) {
    const int st = k0 >> 5;           // step index
    const int sb = st % 3;
    if (k0 + 32 < K) {
      WAIT_VM5();  // tile st landed (st+1's 5 loads may still be in flight)
    } else {
      WAIT_VM0();
    }
    RAWBAR();  // all waves see tile st; readers of buffer (st+2)%3 all done
    if (k0 + 64 < K) QSTAGE((st + 2) % 3, k0 + 64);
    bf16x8 a[4], b[6];
#pragma unroll
    for (int m = 0; m < 4; ++m)
      a[m] = *(const bf16x8*)&SM[sb * 10240 + (wr * 64 + m * 16 + lr) * 32 + lg * 8];
#pragma unroll
    for (int n = 0; n < 6; ++n)
      b[n] = *(const bf16x8*)&SM[sb * 10240 + 4096 +
                                 (wc * 96 + n * 16 + lr) * 32 + lg * 8];
    __builtin_amdgcn_s_setprio(1);
#pragma unroll
    for (int m = 0; m < 4; ++m)
#pragma unroll
      for (int n = 0; n < 6; ++n)
        acc[m][n] =
            __builtin_amdgcn_mfma_f32_16x16x32_bf16(a[m], b[n], acc[m][n], 0, 0, 0);
    __builtin_amdgcn_s_setprio(0);
  }
#undef QSTAGE

#pragma unroll
  for (int m = 0; m < 4; ++m) {
    int rowg = m0 + wr * 64 + m * 16 + lg * 4;
#pragma unroll
    for (int n = 0; n < 6; ++n) {
      int cg = wc * 96 + n * 16 + lr;
      if (cg < 64) {  // Q (scaled)
        int col = head * 64 + cg;
#pragma unroll
        for (int j = 0; j < 4; ++j)
          qkb[(size_t)(rowg + j) * 2048 + col] = f2bf(acc[m][n][j] * SC2F);
      } else if (cg < 128) {  // K
        int col = 1024 + head * 64 + (cg - 64);
#pragma unroll
        for (int j = 0; j < 4; ++j)
          qkb[(size_t)(rowg + j) * 2048 + col] = f2bf(acc[m][n][j]);
      }
    }
  }
  __syncthreads();
  if (wc == 1) {
#pragma unroll
    for (int m = 0; m < 4; ++m)
#pragma unroll
      for (int n = 2; n < 6; ++n) {
        int v = (n - 2) * 16 + lr;
        int s = wr * 64 + m * 16 + lg * 4;
        u16x4 pk;
#pragma unroll
        for (int j = 0; j < 4; ++j) pk[j] = f2bf(acc[m][n][j]);
        *(u16x4*)&SM[v * 136 + s] = pk;
      }
  }
  __syncthreads();
  const int bb2 = m0 >> 11, s0g = m0 & 2047;
  u16* vdst = Vt + ((size_t)(bb2 * 1024 + head * 64)) * 2048 + s0g;
#pragma unroll
  for (int q = 0; q < 4; ++q) {
    int id = q * 256 + t;
    int v = id >> 4, sc = id & 15;
    bf16x8 row = *(const bf16x8*)&SM[v * 136 + sc * 8];
    *(bf16x8*)(vdst + (size_t)v * 2048 + sc * 8) = row;
  }
}

// ---------------- out-proj GEMM: 64x128 tile, single-barrier loop --------
__global__ __launch_bounds__(256) void gemm_out(const u16* __restrict__ A,
                                                const u16* __restrict__ Bt,
                                                float* __restrict__ C, int M,
                                                int N, int K) {
  const int t = threadIdx.x;
  const int lane = t & 63, w = t >> 6;
  const int lr = lane & 15, lg = lane >> 4;
  const int wr = w >> 1, wc = w & 1;
  int lin = blockIdx.y * gridDim.x + blockIdx.x;
  int nwg = gridDim.x * gridDim.y;
  int swz = (lin & 7) * (nwg >> 3) + (lin >> 3);
  int bx = swz % gridDim.x, by = swz / gridDim.x;
  const int m0 = by * 64, n0 = bx * 128;
  __shared__ __align__(16) u16 As[2][64 * 32];
  __shared__ __align__(16) u16 Bs[2][128 * 32];
  const int r0 = t >> 2, cb = (t & 3) * 8;
  const u16* a0 = A + (size_t)(m0 + r0) * K + cb;
  const u16* b0 = Bt + (size_t)(n0 + r0) * K + cb;
  const size_t rowjmp = (size_t)64 * K;
  f32x4 acc[2][4] = {};

#define GSTAGE(bb, k0)                                      \
  {                                                         \
    GLDS16(a0 + (k0), &As[bb][t * 8]);                      \
    GLDS16(b0 + (k0), &Bs[bb][t * 8]);                      \
    GLDS16(b0 + rowjmp + (k0), &Bs[bb][2048 + t * 8]);      \
  }

  GSTAGE(0, 0);
  for (int k0 = 0; k0 < K; k0 += 32) {
    const int bb = (k0 >> 5) & 1;
    WAIT_VM0();
    RAWBAR();
    if (k0 + 32 < K) GSTAGE(bb ^ 1, k0 + 32);
    bf16x8 a[2], b[4];
#pragma unroll
    for (int m = 0; m < 2; ++m)
      a[m] = *(const bf16x8*)&As[bb][(wr * 32 + m * 16 + lr) * 32 + lg * 8];
#pragma unroll
    for (int n = 0; n < 4; ++n)
      b[n] = *(const bf16x8*)&Bs[bb][(wc * 64 + n * 16 + lr) * 32 + lg * 8];
    __builtin_amdgcn_s_setprio(1);
#pragma unroll
    for (int m = 0; m < 2; ++m)
#pragma unroll
      for (int n = 0; n < 4; ++n)
        acc[m][n] =
            __builtin_amdgcn_mfma_f32_16x16x32_bf16(a[m], b[n], acc[m][n], 0, 0, 0);
    __builtin_amdgcn_s_setprio(0);
  }
#undef GSTAGE

#pragma unroll
  for (int m = 0; m < 2; ++m) {
    int rowg = m0 + wr * 32 + m * 16 + lg * 4;
#pragma unroll
    for (int n = 0; n < 4; ++n) {
      int colg = n0 + wc * 64 + n * 16 + lr;
#pragma unroll
      for (int j = 0; j < 4; ++j)
        C[(size_t)(rowg + j) * N + colg] = acc[m][n][j];
    }
  }
}

// ---------------- flash attention: QBLK=128, KVBLK=128, ones-column l -----
// (R17 green, unchanged) Single-barrier pipeline; defer-max every 4th tile.
__global__ __launch_bounds__(256, 2) void attn(const u16* __restrict__ qkb,
                                               const u16* __restrict__ vtb,
                                               u16* __restrict__ hb) {
  const int t = threadIdx.x, lane = t & 63, w = t >> 6;
  const int lr = lane & 15, lg = lane >> 4;
  int lin = blockIdx.x;
  int swz2 = (lin & 7) * 64 + (lin >> 3);  // XCD locality
  int qi = swz2 & 15, bh = swz2 >> 4;
  int b = bh >> 4, h = bh & 15;
  int q0 = qi * 128;
  __shared__ __align__(16) u16 Ks[2][128 * 64];
  __shared__ __align__(16) u16 Vts[2][64 * 128];
  __shared__ __align__(16) u32 Ps[4][2][512];

  bf16x8 qf[2][2];
#pragma unroll
  for (int g = 0; g < 2; ++g) {
    const u16* qb =
        qkb + (size_t)(b * 2048 + q0 + w * 32 + g * 16 + lr) * 2048 + h * 64;
    qf[g][0] = *(const bf16x8*)(qb + lg * 8);
    qf[g][1] = *(const bf16x8*)(qb + 32 + lg * 8);
  }
  bf16x8 ones;
#pragma unroll
  for (int i = 0; i < 8; ++i) ones[i] = (short)0x3F80;  // bf16 1.0

  f32x4 oacc[2][4] = {};
  f32x4 le0 = {}, le1 = {};  // softmax denominators (ones-column PV)
  float mrun0 = -1e30f, mrun1 = -1e30f;

  int chk[2], chv[4];
#pragma unroll
  for (int kk = 0; kk < 2; ++kk) chk[kk] = ((kk * 4 + lg) ^ (lr & 7)) * 8;
#pragma unroll
  for (int kk = 0; kk < 4; ++kk) chv[kk] = ((kk * 4 + lg) ^ lr) * 8;
  const int xw = (lr & 7) << 2;

  const int rk = t >> 3, ck = t & 7;
  const int rv = t >> 4, cv = t & 15;
  const u16* Kg = qkb + (size_t)(b * 2048) * 2048 + 1024 + h * 64;
  const u16* Vg = vtb + (size_t)(b * 1024 + h * 64) * 2048;
  const u16* kp0 = Kg + (size_t)rk * 2048 + ((ck ^ (rk & 7)) * 8);
  const u16* vp0 = Vg + (size_t)rv * 2048 + ((cv ^ (rv & 15)) * 8);
  u32* Pw0 = &Ps[w][0][0];
  u32* Pw1 = &Ps[w][1][0];

#define ASTAGE(bb, tv)                                 \
  {                                                    \
    const u16* kp = kp0 + (size_t)(tv)*262144;         \
    const u16* vp = vp0 + (tv)*128;                    \
    GLDS16(kp, &Ks[bb][t * 8]);                        \
    GLDS16(kp + 65536, &Ks[bb][2048 + t * 8]);         \
    GLDS16(kp + 131072, &Ks[bb][4096 + t * 8]);        \
    GLDS16(kp + 196608, &Ks[bb][6144 + t * 8]);        \
    GLDS16(vp, &Vts[bb][t * 8]);                       \
    GLDS16(vp + 32768, &Vts[bb][2048 + t * 8]);        \
    GLDS16(vp + 65536, &Vts[bb][4096 + t * 8]);        \
    GLDS16(vp + 98304, &Vts[bb][6144 + t * 8]);        \
  }

  ASTAGE(0, 0);
  for (int tv = 0; tv < 16; ++tv) {
    const int bb = tv & 1;
    WAIT_VM0();  // own tile-tv loads landed (issued last iter)
    RAWBAR();    // all landed; all waves done reading buffer bb^1
    if (tv < 15) ASTAGE(bb ^ 1, tv + 1);

    f32x4 s0[8], s1[8];
#pragma unroll
    for (int n = 0; n < 8; ++n) {
      s0[n] = (f32x4){0.f, 0.f, 0.f, 0.f};
      s1[n] = (f32x4){0.f, 0.f, 0.f, 0.f};
    }
    __builtin_amdgcn_s_setprio(1);
#pragma unroll
    for (int kk = 0; kk < 2; ++kk)
#pragma unroll
      for (int n = 0; n < 8; ++n) {
        bf16x8 kf = *(const bf16x8*)&Ks[bb][n * 1024 + lr * 64 + chk[kk]];
        s0[n] = __builtin_amdgcn_mfma_f32_16x16x32_bf16(kf, qf[0][kk], s0[n], 0, 0, 0);
        s1[n] = __builtin_amdgcn_mfma_f32_16x16x32_bf16(kf, qf[1][kk], s1[n], 0, 0, 0);
      }
    __builtin_amdgcn_s_setprio(0);

    if ((tv & 3) == 0) {  // defer-max check every 4th tile
      float t0[8], t1[8];
#pragma unroll
      for (int n = 0; n < 8; ++n) {
        t0[n] = fmaxf(fmaxf(s0[n][0], s0[n][1]), fmaxf(s0[n][2], s0[n][3]));
        t1[n] = fmaxf(fmaxf(s1[n][0], s1[n][1]), fmaxf(s1[n][2], s1[n][3]));
      }
      float pm0 = fmaxf(fmaxf(fmaxf(t0[0], t0[1]), fmaxf(t0[2], t0[3])),
                        fmaxf(fmaxf(t0[4], t0[5]), fmaxf(t0[6], t0[7])));
      float pm1 = fmaxf(fmaxf(fmaxf(t1[0], t1[1]), fmaxf(t1[2], t1[3])),
                        fmaxf(fmaxf(t1[4], t1[5]), fmaxf(t1[6], t1[7])));
      pm0 = fmaxf(pm0, __shfl_xor(pm0, 16));
      pm0 = fmaxf(pm0, __shfl_xor(pm0, 32));
      pm1 = fmaxf(pm1, __shfl_xor(pm1, 16));
      pm1 = fmaxf(pm1, __shfl_xor(pm1, 32));

      if (__any(fmaxf(pm0 - mrun0, pm1 - mrun1) > 8.0f)) {  // T13 defer-max
        {
          float mn = fmaxf(mrun0, pm0);
          float al = __builtin_amdgcn_exp2f(mrun0 - mn);
          float alj[4];
#pragma unroll
          for (int j = 0; j < 4; ++j) alj[j] = __shfl(al, 4 * lg + j);
#pragma unroll
          for (int j = 0; j < 4; ++j) le0[j] *= alj[j];
#pragma unroll
          for (int n = 0; n < 4; ++n)
#pragma unroll
            for (int j = 0; j < 4; ++j) oacc[0][n][j] *= alj[j];
          mrun0 = mn;
        }
        {
          float mn = fmaxf(mrun1, pm1);
          float al = __builtin_amdgcn_exp2f(mrun1 - mn);
          float alj[4];
#pragma unroll
          for (int j = 0; j < 4; ++j) alj[j] = __shfl(al, 4 * lg + j);
#pragma unroll
          for (int j = 0; j < 4; ++j) le1[j] *= alj[j];
#pragma unroll
          for (int n = 0; n < 4; ++n)
#pragma unroll
            for (int j = 0; j < 4; ++j) oacc[1][n][j] *= alj[j];
          mrun1 = mn;
        }
      }
    }

    // ---- pass A: k 0..63 ----
#pragma unroll
    for (int n = 0; n < 4; ++n) {
      float v0 = __builtin_amdgcn_exp2f(s0[n][0] - mrun0);
      float v1 = __builtin_amdgcn_exp2f(s0[n][1] - mrun0);
      float v2 = __builtin_amdgcn_exp2f(s0[n][2] - mrun0);
      float v3 = __builtin_amdgcn_exp2f(s0[n][3] - mrun0);
      Pw0[lr * 32 + ((8 * n + 2 * lg) ^ xw)] = cvt_pk(v0, v1);
      Pw0[lr * 32 + ((8 * n + 2 * lg + 1) ^ xw)] = cvt_pk(v2, v3);
      float u0 = __builtin_amdgcn_exp2f(s1[n][0] - mrun1);
      float u1 = __builtin_amdgcn_exp2f(s1[n][1] - mrun1);
      float u2 = __builtin_amdgcn_exp2f(s1[n][2] - mrun1);
      float u3 = __builtin_amdgcn_exp2f(s1[n][3] - mrun1);
      Pw1[lr * 32 + ((8 * n + 2 * lg) ^ xw)] = cvt_pk(u0, u1);
      Pw1[lr * 32 + ((8 * n + 2 * lg + 1) ^ xw)] = cvt_pk(u2, u3);
    }
    __builtin_amdgcn_s_setprio(1);
#pragma unroll
    for (int kk = 0; kk < 2; ++kk) {
      bf16x8 pa0 = *(const bf16x8*)&Pw0[lr * 32 + ((16 * kk + 4 * lg) ^ xw)];
      bf16x8 pa1 = *(const bf16x8*)&Pw1[lr * 32 + ((16 * kk + 4 * lg) ^ xw)];
      le0 = __builtin_amdgcn_mfma_f32_16x16x32_bf16(pa0, ones, le0, 0, 0, 0);
      le1 = __builtin_amdgcn_mfma_f32_16x16x32_bf16(pa1, ones, le1, 0, 0, 0);
#pragma unroll
      for (int n = 0; n < 4; ++n) {
        bf16x8 vf = *(const bf16x8*)&Vts[bb][n * 2048 + lr * 128 + chv[kk]];
        oacc[0][n] = __builtin_amdgcn_mfma_f32_16x16x32_bf16(pa0, vf, oacc[0][n], 0, 0, 0);
        oacc[1][n] = __builtin_amdgcn_mfma_f32_16x16x32_bf16(pa1, vf, oacc[1][n], 0, 0, 0);
      }
    }
    __builtin_amdgcn_s_setprio(0);
    // ---- pass B: k 64..127 (reuse Ps; same-wave DS in-order) ----
#pragma unroll
    for (int n = 4; n < 8; ++n) {
      float v0 = __builtin_amdgcn_exp2f(s0[n][0] - mrun0);
      float v1 = __builtin_amdgcn_exp2f(s0[n][1] - mrun0);
      float v2 = __builtin_amdgcn_exp2f(s0[n][2] - mrun0);
      float v3 = __builtin_amdgcn_exp2f(s0[n][3] - mrun0);
      Pw0[lr * 32 + ((8 * (n - 4) + 2 * lg) ^ xw)] = cvt_pk(v0, v1);
      Pw0[lr * 32 + ((8 * (n - 4) + 2 * lg + 1) ^ xw)] = cvt_pk(v2, v3);
      float u0 = __builtin_amdgcn_exp2f(s1[n][0] - mrun1);
      float u1 = __builtin_amdgcn_exp2f(s1[n][1] - mrun1);
      float u2 = __builtin_amdgcn_exp2f(s1[n][2] - mrun1);
      float u3 = __builtin_amdgcn_exp2f(s1[n][3] - mrun1);
      Pw1[lr * 32 + ((8 * (n - 4) + 2 * lg) ^ xw)] = cvt_pk(u0, u1);
      Pw1[lr * 32 + ((8 * (n - 4) + 2 * lg + 1) ^ xw)] = cvt_pk(u2, u3);
    }
    __builtin_amdgcn_s_setprio(1);
#pragma unroll
    for (int kk = 2; kk < 4; ++kk) {
      bf16x8 pa0 = *(const bf16x8*)&Pw0[lr * 32 + ((16 * (kk - 2) + 4 * lg) ^ xw)];
      bf16x8 pa1 = *(const bf16x8*)&Pw1[lr * 32 + ((16 * (kk - 2) + 4 * lg) ^ xw)];
      le0 = __builtin_amdgcn_mfma_f32_16x16x32_bf16(pa0, ones, le0, 0, 0, 0);
      le1 = __builtin_amdgcn_mfma_f32_16x16x32_bf16(pa1, ones, le1, 0, 0, 0);
#pragma unroll
      for (int n = 0; n < 4; ++n) {
        bf16x8 vf = *(const bf16x8*)&Vts[bb][n * 2048 + lr * 128 + chv[kk]];
        oacc[0][n] = __builtin_amdgcn_mfma_f32_16x16x32_bf16(pa0, vf, oacc[0][n], 0, 0, 0);
        oacc[1][n] = __builtin_amdgcn_mfma_f32_16x16x32_bf16(pa1, vf, oacc[1][n], 0, 0, 0);
      }
    }
    __builtin_amdgcn_s_setprio(0);
  }
#undef ASTAGE

  // epilogue: per-lane rcp of the ones-column accumulators (no shuffles)
  float rj0[4], rj1[4];
#pragma unroll
  for (int j = 0; j < 4; ++j) {
    rj0[j] = __builtin_amdgcn_rcpf(le0[j]);
    rj1[j] = __builtin_amdgcn_rcpf(le1[j]);
  }
  int row0 = b * 2048 + q0 + w * 32 + lg * 4;
#pragma unroll
  for (int n = 0; n < 4; ++n) {
    int col = h * 64 + n * 16 + lr;
#pragma unroll
    for (int j = 0; j < 4; ++j) {
      hb[(size_t)(row0 + j) * 1024 + col] = f2bf(oacc[0][n][j] * rj0[j]);
      hb[(size_t)(row0 + 16 + j) * 1024 + col] = f2bf(oacc[1][n][j] * rj1[j]);
    }
  }
}

extern "C" void kernel_launch(void* const* d_in, const int* in_sizes, int n_in,
                              void* d_out, int out_size, void* d_ws,
                              size_t ws_size, hipStream_t stream) {
  const float* x = (const float*)d_in[0];
  const float* wq = (const float*)d_in[1];
  const float* wk = (const float*)d_in[2];
  const float* wv = (const float*)d_in[3];
  const float* wo = (const float*)d_in[4];

  u16* xb = (u16*)d_ws;              // [4096][1024]        4M
  u16* wqkv = xb + 4 * 1024 * 1024;  // [3072][1024]        3M
  u16* wot = wqkv + 3 * 1024 * 1024; // [1024][1024]        1M
  u16* qkb = wot + 1024 * 1024;      // [4096][2048] Q|K    8M
  u16* vtb = qkb + 8 * 1024 * 1024;  // [2][1024][2048] Vt  4M
  u16* hb = vtb + 4 * 1024 * 1024;   // [4096][1024] heads  4M

  cast_all<<<3072, 256, 0, stream>>>(x, wq, wk, wv, wo, xb, wqkv, wot);
  gemm_qkv<<<dim3(16, 32), 256, 0, stream>>>(xb, wqkv, qkb, vtb, 4096, 3072, 1024);
  attn<<<512, 256, 0, stream>>>(qkb, vtb, hb);
  gemm_out<<<dim3(8, 64), 256, 0, stream>>>(hb, wot, (float*)d_out, 4096, 1024, 1024);
}

// Round 19
// 111.366 us; speedup vs baseline: 1.0129x; 1.0129x over previous
//
#include <hip/hip_runtime.h>

typedef __attribute__((ext_vector_type(8))) short bf16x8;
typedef __attribute__((ext_vector_type(4))) float f32x4;
typedef __attribute__((ext_vector_type(4))) unsigned short u16x4;
typedef unsigned short u16;
typedef unsigned int u32;

static __device__ __forceinline__ u16 f2bf(float f) {
  u32 u = __float_as_uint(f);
  u32 r = (u + 0x7fffu + ((u >> 16) & 1u)) >> 16;  // RNE
  return (u16)r;
}

static __device__ __forceinline__ u32 cvt_pk(float lo, float hi) {
  u32 r;
  asm("v_cvt_pk_bf16_f32 %0, %1, %2" : "=v"(r) : "v"(lo), "v"(hi));
  return r;
}

#define GLDS16(g, l)                                                        \
  __builtin_amdgcn_global_load_lds(                                         \
      (const __attribute__((address_space(1))) u32*)(g),                    \
      (__attribute__((address_space(3))) u32*)(l), 16, 0, 0)

#define WAIT_VM0() asm volatile("s_waitcnt vmcnt(0)" ::: "memory")
#define RAWBAR() __builtin_amdgcn_s_barrier()

#define SC2F 0.18033688011112042f  // 0.125 * log2(e)

// ---------------- fused cast kernel ----------------
__global__ __launch_bounds__(256) void cast_all(const float* __restrict__ x,
                                                const float* __restrict__ wq,
                                                const float* __restrict__ wk,
                                                const float* __restrict__ wv,
                                                const float* __restrict__ wo,
                                                u16* __restrict__ xb,
                                                u16* __restrict__ wqkv,
                                                u16* __restrict__ wot) {
  __shared__ u16 tile[64][66];
  int bid = blockIdx.x, t = threadIdx.x;
  if (bid < 2048) {
    int i = bid * 256 + t;
    const float4* xv = (const float4*)x;
    float4 a = xv[i * 2], b = xv[i * 2 + 1];
    bf16x8 o;
    o[0] = f2bf(a.x); o[1] = f2bf(a.y); o[2] = f2bf(a.z); o[3] = f2bf(a.w);
    o[4] = f2bf(b.x); o[5] = f2bf(b.y); o[6] = f2bf(b.z); o[7] = f2bf(b.w);
    *(bf16x8*)(xb + i * 8) = o;
    return;
  }
  const float* src;
  u16* dstb;
  if (bid < 2816) {
    int id = bid - 2048;  // 768 = sel(3) * h(16) * dt(16)
    int dt = id & 15, h = (id >> 4) & 15, sel = id >> 8;
    src = (sel == 0 ? wq : (sel == 1 ? wk : wv)) + h * 65536 + dt * 4096;
    dstb = wqkv + ((size_t)(h * 192 + sel * 64)) * 1024 + dt * 64;
    int r = t >> 4, c4 = (t & 15) * 4;
#pragma unroll
    for (int p = 0; p < 4; ++p) {
      int rr = r + p * 16;
      float4 v = *(const float4*)(src + rr * 64 + c4);
      u16x4 o;
      o[0] = f2bf(v.x); o[1] = f2bf(v.y); o[2] = f2bf(v.z); o[3] = f2bf(v.w);
      *(u16x4*)&tile[rr][c4] = o;  // tile[d][kk]
    }
  } else {
    int id = bid - 2816;  // 256 = kt(16) * nt(16)
    int nt = id & 15, kt = id >> 4;
    src = wo + (size_t)(kt * 64) * 1024 + nt * 64;
    dstb = wot + (size_t)(nt * 64) * 1024 + kt * 64;
    int r = t >> 4, c4 = (t & 15) * 4;
#pragma unroll
    for (int p = 0; p < 4; ++p) {
      int rr = r + p * 16;
      float4 v = *(const float4*)(src + (size_t)rr * 1024 + c4);
      u16x4 o;
      o[0] = f2bf(v.x); o[1] = f2bf(v.y); o[2] = f2bf(v.z); o[3] = f2bf(v.w);
      *(u16x4*)&tile[rr][c4] = o;
    }
  }
  __syncthreads();
  int nn = t >> 3, dc = (t & 7) * 8;
#pragma unroll
  for (int p = 0; p < 2; ++p) {
    int np = nn + p * 32;
    u16x4 a, b2;
#pragma unroll
    for (int i = 0; i < 4; ++i) {
      a[i] = tile[dc + i][np];
      b2[i] = tile[dc + 4 + i][np];
    }
    *(u16x4*)(dstb + (size_t)np * 1024 + dc) = a;
    *(u16x4*)(dstb + (size_t)np * 1024 + dc + 4) = b2;
  }
}

// ---------------- QKV GEMM: 128x192 tile, BK=64, swizzled LDS ------------
// Single-barrier pipeline. XCD grouping is bx-major: each XCD owns 2 bx
// columns x all 32 by rows, so the 768KB B-panel stays L2-resident.
__global__ __launch_bounds__(256) void gemm_qkv(const u16* __restrict__ A,
                                                const u16* __restrict__ Bt,
                                                u16* __restrict__ qkb,
                                                u16* __restrict__ Vt, int M,
                                                int N, int K) {
  const int t = threadIdx.x;
  const int lane = t & 63, w = t >> 6;
  const int lr = lane & 15, lg = lane >> 4;
  const int wr = w >> 1, wc = w & 1;
  int lin = blockIdx.y * gridDim.x + blockIdx.x;
  // bx-major XCD grouping (bijective for 512 = 8 * 2 * 32)
  int bx = 2 * (lin & 7) + ((lin >> 3) & 1);
  int by = lin >> 4;
  const int m0 = by * 128, n0 = bx * 192, head = bx;
  __shared__ __align__(16) u16 SM[40960];
  const int rs = t >> 3, cs = t & 7;
  const int sw = (cs ^ (rs & 7)) * 8;
  const u16* a0 = A + (size_t)(m0 + rs) * K + sw;
  const u16* b0 = Bt + (size_t)(n0 + rs) * K + sw;
  int chk[2];
#pragma unroll
  for (int kk = 0; kk < 2; ++kk) chk[kk] = ((kk * 4 + lg) ^ (lr & 7)) * 8;
  f32x4 acc[4][6] = {};

#define QSTAGE(bb, k0)                                                     \
  {                                                                        \
    _Pragma("unroll") for (int p = 0; p < 4; ++p)                          \
        GLDS16(a0 + (size_t)p * 32 * K + (k0),                             \
               &SM[(bb)*8192 + (p * 256 + t) * 8]);                        \
    _Pragma("unroll") for (int p = 0; p < 6; ++p)                          \
        GLDS16(b0 + (size_t)p * 32 * K + (k0),                             \
               &SM[16384 + (bb)*12288 + (p * 256 + t) * 8]);               \
  }

  QSTAGE(0, 0);
  for (int k0 = 0; k0 < K; k0 += 64) {
    const int bb = (k0 >> 6) & 1;
    WAIT_VM0();  // own tile-k0 loads landed (issued last iter)
    RAWBAR();    // all waves' loads landed; all done reading buffer bb^1
    if (k0 + 64 < K) QSTAGE(bb ^ 1, k0 + 64);
#pragma unroll
    for (int kk = 0; kk < 2; ++kk) {
      bf16x8 a[4], b[6];
#pragma unroll
      for (int m = 0; m < 4; ++m)
        a[m] = *(const bf16x8*)&SM[bb * 8192 + (wr * 64 + m * 16 + lr) * 64 + chk[kk]];
#pragma unroll
      for (int n = 0; n < 6; ++n)
        b[n] = *(const bf16x8*)&SM[16384 + bb * 12288 +
                                   (wc * 96 + n * 16 + lr) * 64 + chk[kk]];
      __builtin_amdgcn_s_setprio(1);
#pragma unroll
      for (int m = 0; m < 4; ++m)
#pragma unroll
        for (int n = 0; n < 6; ++n)
          acc[m][n] =
              __builtin_amdgcn_mfma_f32_16x16x32_bf16(a[m], b[n], acc[m][n], 0, 0, 0);
      __builtin_amdgcn_s_setprio(0);
    }
  }
#undef QSTAGE

#pragma unroll
  for (int m = 0; m < 4; ++m) {
    int rowg = m0 + wr * 64 + m * 16 + lg * 4;
#pragma unroll
    for (int n = 0; n < 6; ++n) {
      int cg = wc * 96 + n * 16 + lr;
      if (cg < 64) {  // Q (scaled)
        int col = head * 64 + cg;
#pragma unroll
        for (int j = 0; j < 4; ++j)
          qkb[(size_t)(rowg + j) * 2048 + col] = f2bf(acc[m][n][j] * SC2F);
      } else if (cg < 128) {  // K
        int col = 1024 + head * 64 + (cg - 64);
#pragma unroll
        for (int j = 0; j < 4; ++j)
          qkb[(size_t)(rowg + j) * 2048 + col] = f2bf(acc[m][n][j]);
      }
    }
  }
  __syncthreads();
  if (wc == 1) {
#pragma unroll
    for (int m = 0; m < 4; ++m)
#pragma unroll
      for (int n = 2; n < 6; ++n) {
        int v = (n - 2) * 16 + lr;
        int s = wr * 64 + m * 16 + lg * 4;
        u16x4 pk;
#pragma unroll
        for (int j = 0; j < 4; ++j) pk[j] = f2bf(acc[m][n][j]);
        *(u16x4*)&SM[v * 136 + s] = pk;
      }
  }
  __syncthreads();
  const int bb2 = m0 >> 11, s0g = m0 & 2047;
  u16* vdst = Vt + ((size_t)(bb2 * 1024 + head * 64)) * 2048 + s0g;
#pragma unroll
  for (int q = 0; q < 4; ++q) {
    int id = q * 256 + t;
    int v = id >> 4, sc = id & 15;
    bf16x8 row = *(const bf16x8*)&SM[v * 136 + sc * 8];
    *(bf16x8*)(vdst + (size_t)v * 2048 + sc * 8) = row;
  }
}

// ---------------- out-proj GEMM: 64x128 tile, single-barrier loop --------
__global__ __launch_bounds__(256) void gemm_out(const u16* __restrict__ A,
                                                const u16* __restrict__ Bt,
                                                float* __restrict__ C, int M,
                                                int N, int K) {
  const int t = threadIdx.x;
  const int lane = t & 63, w = t >> 6;
  const int lr = lane & 15, lg = lane >> 4;
  const int wr = w >> 1, wc = w & 1;
  int lin = blockIdx.y * gridDim.x + blockIdx.x;
  int nwg = gridDim.x * gridDim.y;
  int swz = (lin & 7) * (nwg >> 3) + (lin >> 3);
  int bx = swz % gridDim.x, by = swz / gridDim.x;
  const int m0 = by * 64, n0 = bx * 128;
  __shared__ __align__(16) u16 As[2][64 * 32];
  __shared__ __align__(16) u16 Bs[2][128 * 32];
  const int r0 = t >> 2, cb = (t & 3) * 8;
  const u16* a0 = A + (size_t)(m0 + r0) * K + cb;
  const u16* b0 = Bt + (size_t)(n0 + r0) * K + cb;
  const size_t rowjmp = (size_t)64 * K;
  f32x4 acc[2][4] = {};

#define GSTAGE(bb, k0)                                      \
  {                                                         \
    GLDS16(a0 + (k0), &As[bb][t * 8]);                      \
    GLDS16(b0 + (k0), &Bs[bb][t * 8]);                      \
    GLDS16(b0 + rowjmp + (k0), &Bs[bb][2048 + t * 8]);      \
  }

  GSTAGE(0, 0);
  for (int k0 = 0; k0 < K; k0 += 32) {
    const int bb = (k0 >> 5) & 1;
    WAIT_VM0();
    RAWBAR();
    if (k0 + 32 < K) GSTAGE(bb ^ 1, k0 + 32);
    bf16x8 a[2], b[4];
#pragma unroll
    for (int m = 0; m < 2; ++m)
      a[m] = *(const bf16x8*)&As[bb][(wr * 32 + m * 16 + lr) * 32 + lg * 8];
#pragma unroll
    for (int n = 0; n < 4; ++n)
      b[n] = *(const bf16x8*)&Bs[bb][(wc * 64 + n * 16 + lr) * 32 + lg * 8];
    __builtin_amdgcn_s_setprio(1);
#pragma unroll
    for (int m = 0; m < 2; ++m)
#pragma unroll
      for (int n = 0; n < 4; ++n)
        acc[m][n] =
            __builtin_amdgcn_mfma_f32_16x16x32_bf16(a[m], b[n], acc[m][n], 0, 0, 0);
    __builtin_amdgcn_s_setprio(0);
  }
#undef GSTAGE

#pragma unroll
  for (int m = 0; m < 2; ++m) {
    int rowg = m0 + wr * 32 + m * 16 + lg * 4;
#pragma unroll
    for (int n = 0; n < 4; ++n) {
      int colg = n0 + wc * 64 + n * 16 + lr;
#pragma unroll
      for (int j = 0; j < 4; ++j)
        C[(size_t)(rowg + j) * N + colg] = acc[m][n][j];
    }
  }
}

// ---------------- flash attention: QBLK=128, KVBLK=128, ones-column l -----
// Single-barrier pipeline; defer-max check every 4th tile (worst-case
// P ~ exp2(18) — safe in f32/bf16; softmax ratios exact).
__global__ __launch_bounds__(256, 2) void attn(const u16* __restrict__ qkb,
                                               const u16* __restrict__ vtb,
                                               u16* __restrict__ hb) {
  const int t = threadIdx.x, lane = t & 63, w = t >> 6;
  const int lr = lane & 15, lg = lane >> 4;
  int lin = blockIdx.x;
  int swz2 = (lin & 7) * 64 + (lin >> 3);  // XCD locality
  int qi = swz2 & 15, bh = swz2 >> 4;
  int b = bh >> 4, h = bh & 15;
  int q0 = qi * 128;
  __shared__ __align__(16) u16 Ks[2][128 * 64];
  __shared__ __align__(16) u16 Vts[2][64 * 128];
  __shared__ __align__(16) u32 Ps[4][2][512];

  bf16x8 qf[2][2];
#pragma unroll
  for (int g = 0; g < 2; ++g) {
    const u16* qb =
        qkb + (size_t)(b * 2048 + q0 + w * 32 + g * 16 + lr) * 2048 + h * 64;
    qf[g][0] = *(const bf16x8*)(qb + lg * 8);
    qf[g][1] = *(const bf16x8*)(qb + 32 + lg * 8);
  }
  bf16x8 ones;
#pragma unroll
  for (int i = 0; i < 8; ++i) ones[i] = (short)0x3F80;  // bf16 1.0

  f32x4 oacc[2][4] = {};
  f32x4 le0 = {}, le1 = {};  // softmax denominators (ones-column PV)
  float mrun0 = -1e30f, mrun1 = -1e30f;

  int chk[2], chv[4];
#pragma unroll
  for (int kk = 0; kk < 2; ++kk) chk[kk] = ((kk * 4 + lg) ^ (lr & 7)) * 8;
#pragma unroll
  for (int kk = 0; kk < 4; ++kk) chv[kk] = ((kk * 4 + lg) ^ lr) * 8;
  const int xw = (lr & 7) << 2;

  const int rk = t >> 3, ck = t & 7;
  const int rv = t >> 4, cv = t & 15;
  const u16* Kg = qkb + (size_t)(b * 2048) * 2048 + 1024 + h * 64;
  const u16* Vg = vtb + (size_t)(b * 1024 + h * 64) * 2048;
  const u16* kp0 = Kg + (size_t)rk * 2048 + ((ck ^ (rk & 7)) * 8);
  const u16* vp0 = Vg + (size_t)rv * 2048 + ((cv ^ (rv & 15)) * 8);
  u32* Pw0 = &Ps[w][0][0];
  u32* Pw1 = &Ps[w][1][0];

#define ASTAGE(bb, tv)                                 \
  {                                                    \
    const u16* kp = kp0 + (size_t)(tv)*262144;         \
    const u16* vp = vp0 + (tv)*128;                    \
    GLDS16(kp, &Ks[bb][t * 8]);                        \
    GLDS16(kp + 65536, &Ks[bb][2048 + t * 8]);         \
    GLDS16(kp + 131072, &Ks[bb][4096 + t * 8]);        \
    GLDS16(kp + 196608, &Ks[bb][6144 + t * 8]);        \
    GLDS16(vp, &Vts[bb][t * 8]);                       \
    GLDS16(vp + 32768, &Vts[bb][2048 + t * 8]);        \
    GLDS16(vp + 65536, &Vts[bb][4096 + t * 8]);        \
    GLDS16(vp + 98304, &Vts[bb][6144 + t * 8]);        \
  }

  ASTAGE(0, 0);
  for (int tv = 0; tv < 16; ++tv) {
    const int bb = tv & 1;
    WAIT_VM0();  // own tile-tv loads landed (issued last iter)
    RAWBAR();    // all landed; all waves done reading buffer bb^1
    if (tv < 15) ASTAGE(bb ^ 1, tv + 1);

    f32x4 s0[8], s1[8];
#pragma unroll
    for (int n = 0; n < 8; ++n) {
      s0[n] = (f32x4){0.f, 0.f, 0.f, 0.f};
      s1[n] = (f32x4){0.f, 0.f, 0.f, 0.f};
    }
    __builtin_amdgcn_s_setprio(1);
#pragma unroll
    for (int kk = 0; kk < 2; ++kk)
#pragma unroll
      for (int n = 0; n < 8; ++n) {
        bf16x8 kf = *(const bf16x8*)&Ks[bb][n * 1024 + lr * 64 + chk[kk]];
        s0[n] = __builtin_amdgcn_mfma_f32_16x16x32_bf16(kf, qf[0][kk], s0[n], 0, 0, 0);
        s1[n] = __builtin_amdgcn_mfma_f32_16x16x32_bf16(kf, qf[1][kk], s1[n], 0, 0, 0);
      }
    __builtin_amdgcn_s_setprio(0);

    if ((tv & 3) == 0) {  // defer-max check every 4th tile
      float t0[8], t1[8];
#pragma unroll
      for (int n = 0; n < 8; ++n) {
        t0[n] = fmaxf(fmaxf(s0[n][0], s0[n][1]), fmaxf(s0[n][2], s0[n][3]));
        t1[n] = fmaxf(fmaxf(s1[n][0], s1[n][1]), fmaxf(s1[n][2], s1[n][3]));
      }
      float pm0 = fmaxf(fmaxf(fmaxf(t0[0], t0[1]), fmaxf(t0[2], t0[3])),
                        fmaxf(fmaxf(t0[4], t0[5]), fmaxf(t0[6], t0[7])));
      float pm1 = fmaxf(fmaxf(fmaxf(t1[0], t1[1]), fmaxf(t1[2], t1[3])),
                        fmaxf(fmaxf(t1[4], t1[5]), fmaxf(t1[6], t1[7])));
      pm0 = fmaxf(pm0, __shfl_xor(pm0, 16));
      pm0 = fmaxf(pm0, __shfl_xor(pm0, 32));
      pm1 = fmaxf(pm1, __shfl_xor(pm1, 16));
      pm1 = fmaxf(pm1, __shfl_xor(pm1, 32));

      if (__any(fmaxf(pm0 - mrun0, pm1 - mrun1) > 8.0f)) {  // T13 defer-max
        {
          float mn = fmaxf(mrun0, pm0);
          float al = __builtin_amdgcn_exp2f(mrun0 - mn);
          float alj[4];
#pragma unroll
          for (int j = 0; j < 4; ++j) alj[j] = __shfl(al, 4 * lg + j);
#pragma unroll
          for (int j = 0; j < 4; ++j) le0[j] *= alj[j];
#pragma unroll
          for (int n = 0; n < 4; ++n)
#pragma unroll
            for (int j = 0; j < 4; ++j) oacc[0][n][j] *= alj[j];
          mrun0 = mn;
        }
        {
          float mn = fmaxf(mrun1, pm1);
          float al = __builtin_amdgcn_exp2f(mrun1 - mn);
          float alj[4];
#pragma unroll
          for (int j = 0; j < 4; ++j) alj[j] = __shfl(al, 4 * lg + j);
#pragma unroll
          for (int j = 0; j < 4; ++j) le1[j] *= alj[j];
#pragma unroll
          for (int n = 0; n < 4; ++n)
#pragma unroll
            for (int j = 0; j < 4; ++j) oacc[1][n][j] *= alj[j];
          mrun1 = mn;
        }
      }
    }

    // ---- pass A: k 0..63 ----
#pragma unroll
    for (int n = 0; n < 4; ++n) {
      float v0 = __builtin_amdgcn_exp2f(s0[n][0] - mrun0);
      float v1 = __builtin_amdgcn_exp2f(s0[n][1] - mrun0);
      float v2 = __builtin_amdgcn_exp2f(s0[n][2] - mrun0);
      float v3 = __builtin_amdgcn_exp2f(s0[n][3] - mrun0);
      Pw0[lr * 32 + ((8 * n + 2 * lg) ^ xw)] = cvt_pk(v0, v1);
      Pw0[lr * 32 + ((8 * n + 2 * lg + 1) ^ xw)] = cvt_pk(v2, v3);
      float u0 = __builtin_amdgcn_exp2f(s1[n][0] - mrun1);
      float u1 = __builtin_amdgcn_exp2f(s1[n][1] - mrun1);
      float u2 = __builtin_amdgcn_exp2f(s1[n][2] - mrun1);
      float u3 = __builtin_amdgcn_exp2f(s1[n][3] - mrun1);
      Pw1[lr * 32 + ((8 * n + 2 * lg) ^ xw)] = cvt_pk(u0, u1);
      Pw1[lr * 32 + ((8 * n + 2 * lg + 1) ^ xw)] = cvt_pk(u2, u3);
    }
    __builtin_amdgcn_s_setprio(1);
#pragma unroll
    for (int kk = 0; kk < 2; ++kk) {
      bf16x8 pa0 = *(const bf16x8*)&Pw0[lr * 32 + ((16 * kk + 4 * lg) ^ xw)];
      bf16x8 pa1 = *(const bf16x8*)&Pw1[lr * 32 + ((16 * kk + 4 * lg) ^ xw)];
      le0 = __builtin_amdgcn_mfma_f32_16x16x32_bf16(pa0, ones, le0, 0, 0, 0);
      le1 = __builtin_amdgcn_mfma_f32_16x16x32_bf16(pa1, ones, le1, 0, 0, 0);
#pragma unroll
      for (int n = 0; n < 4; ++n) {
        bf16x8 vf = *(const bf16x8*)&Vts[bb][n * 2048 + lr * 128 + chv[kk]];
        oacc[0][n] = __builtin_amdgcn_mfma_f32_16x16x32_bf16(pa0, vf, oacc[0][n], 0, 0, 0);
        oacc[1][n] = __builtin_amdgcn_mfma_f32_16x16x32_bf16(pa1, vf, oacc[1][n], 0, 0, 0);
      }
    }
    __builtin_amdgcn_s_setprio(0);
    // ---- pass B: k 64..127 (reuse Ps; same-wave DS in-order) ----
#pragma unroll
    for (int n = 4; n < 8; ++n) {
      float v0 = __builtin_amdgcn_exp2f(s0[n][0] - mrun0);
      float v1 = __builtin_amdgcn_exp2f(s0[n][1] - mrun0);
      float v2 = __builtin_amdgcn_exp2f(s0[n][2] - mrun0);
      float v3 = __builtin_amdgcn_exp2f(s0[n][3] - mrun0);
      Pw0[lr * 32 + ((8 * (n - 4) + 2 * lg) ^ xw)] = cvt_pk(v0, v1);
      Pw0[lr * 32 + ((8 * (n - 4) + 2 * lg + 1) ^ xw)] = cvt_pk(v2, v3);
      float u0 = __builtin_amdgcn_exp2f(s1[n][0] - mrun1);
      float u1 = __builtin_amdgcn_exp2f(s1[n][1] - mrun1);
      float u2 = __builtin_amdgcn_exp2f(s1[n][2] - mrun1);
      float u3 = __builtin_amdgcn_exp2f(s1[n][3] - mrun1);
      Pw1[lr * 32 + ((8 * (n - 4) + 2 * lg) ^ xw)] = cvt_pk(u0, u1);
      Pw1[lr * 32 + ((8 * (n - 4) + 2 * lg + 1) ^ xw)] = cvt_pk(u2, u3);
    }
    __builtin_amdgcn_s_setprio(1);
#pragma unroll
    for (int kk = 2; kk < 4; ++kk) {
      bf16x8 pa0 = *(const bf16x8*)&Pw0[lr * 32 + ((16 * (kk - 2) + 4 * lg) ^ xw)];
      bf16x8 pa1 = *(const bf16x8*)&Pw1[lr * 32 + ((16 * (kk - 2) + 4 * lg) ^ xw)];
      le0 = __builtin_amdgcn_mfma_f32_16x16x32_bf16(pa0, ones, le0, 0, 0, 0);
      le1 = __builtin_amdgcn_mfma_f32_16x16x32_bf16(pa1, ones, le1, 0, 0, 0);
#pragma unroll
      for (int n = 0; n < 4; ++n) {
        bf16x8 vf = *(const bf16x8*)&Vts[bb][n * 2048 + lr * 128 + chv[kk]];
        oacc[0][n] = __builtin_amdgcn_mfma_f32_16x16x32_bf16(pa0, vf, oacc[0][n], 0, 0, 0);
        oacc[1][n] = __builtin_amdgcn_mfma_f32_16x16x32_bf16(pa1, vf, oacc[1][n], 0, 0, 0);
      }
    }
    __builtin_amdgcn_s_setprio(0);
  }
#undef ASTAGE

  // epilogue: per-lane rcp of the ones-column accumulators (no shuffles)
  float rj0[4], rj1[4];
#pragma unroll
  for (int j = 0; j < 4; ++j) {
    rj0[j] = __builtin_amdgcn_rcpf(le0[j]);
    rj1[j] = __builtin_amdgcn_rcpf(le1[j]);
  }
  int row0 = b * 2048 + q0 + w * 32 + lg * 4;
#pragma unroll
  for (int n = 0; n < 4; ++n) {
    int col = h * 64 + n * 16 + lr;
#pragma unroll
    for (int j = 0; j < 4; ++j) {
      hb[(size_t)(row0 + j) * 1024 + col] = f2bf(oacc[0][n][j] * rj0[j]);
      hb[(size_t)(row0 + 16 + j) * 1024 + col] = f2bf(oacc[1][n][j] * rj1[j]);
    }
  }
}

extern "C" void kernel_launch(void* const* d_in, const int* in_sizes, int n_in,
                              void* d_out, int out_size, void* d_ws,
                              size_t ws_size, hipStream_t stream) {
  const float* x = (const float*)d_in[0];
  const float* wq = (const float*)d_in[1];
  const float* wk = (const float*)d_in[2];
  const float* wv = (const float*)d_in[3];
  const float* wo = (const float*)d_in[4];

  u16* xb = (u16*)d_ws;              // [4096][1024]        4M
  u16* wqkv = xb + 4 * 1024 * 1024;  // [3072][1024]        3M
  u16* wot = wqkv + 3 * 1024 * 1024; // [1024][1024]        1M
  u16* qkb = wot + 1024 * 1024;      // [4096][2048] Q|K    8M
  u16* vtb = qkb + 8 * 1024 * 1024;  // [2][1024][2048] Vt  4M
  u16* hb = vtb + 4 * 1024 * 1024;   // [4096][1024] heads  4M

  cast_all<<<3072, 256, 0, stream>>>(x, wq, wk, wv, wo, xb, wqkv, wot);
  gemm_qkv<<<dim3(16, 32), 256, 0, stream>>>(xb, wqkv, qkb, vtb, 4096, 3072, 1024);
  attn<<<512, 256, 0, stream>>>(qkb, vtb, hb);
  gemm_out<<<dim3(8, 64), 256, 0, stream>>>(hb, wot, (float*)d_out, 4096, 1024, 1024);
}